// Round 7
// baseline (31.216 us; speedup 1.0000x reference)
//
#include <hip/hip_runtime.h>
#include <math.h>

// Poisson MC estimator. R7: 16B/landmark LDS payload (y0,y1,y2,g) — halves
// the broadcast ds_read_b128 traffic that bounded R4 (4096 -> 2048 per CU)
// — combined with ONLY silicon-validated compute:
//   * pk T-block (3 x v_pk_fma_f32): validated twice on HW (v_hat passed in
//     R5 and R6, and v_hat consumes T -> S -> AV).
//   * everything downstream of S: plain scalar fmaf/fmax/rsq, the exact
//     pattern that passed in R1/R2.
// R5/R6's gradient corruption localized to the packed block-2 asm (gradient-
// only accumulators); it is abandoned, not re-debugged. Scalar block-2 costs
// ~+14cy/landmark vs full-pk but removes the unverifiable VOP3P surface.

#define EPS2    1e-4f
#define INV_4PI 0.07957747154594767f

constexpr int M_LAND = 2048;
constexpr int NW     = 16;                 // waves per block
constexpr int SLICE  = M_LAND / NW;        // 128 landmarks per wave
constexpr int QPB    = 128;                // queries per block (64 lanes x 2)

typedef float f32x2 __attribute__((ext_vector_type(2)));

__global__ __launch_bounds__(1024, 4)
void poisson_r7_kernel(const float* __restrict__ xq,
                       const float* __restrict__ xl,
                       const float* __restrict__ gl,
                       float* __restrict__ out, int B)
{
    __shared__ float4 pack[M_LAND];        // 32 KB: (y0, y1, y2, g)
    __shared__ float  part[NW][QPB][5];    // 40 KB

    const int tid = threadIdx.x;
    for (int j = tid; j < M_LAND; j += 1024)
        pack[j] = make_float4(xl[3*j], xl[3*j+1], xl[3*j+2], gl[j]);

    const int lane  = tid & 63;
    const int w     = tid >> 6;
    const int qbase = blockIdx.x * QPB;
    const int qa    = qbase + lane;
    const int qb    = qbase + 64 + lane;

    const float a0 = xq[3*qa], a1 = xq[3*qa+1], a2 = xq[3*qa+2];
    const float b0 = xq[3*qb], b1 = xq[3*qb+1], b2 = xq[3*qb+2];

    // packed per-lane query state for the T-block: lo = query A, hi = query B
    f32x2 Qn0 = {-2.0f*a0, -2.0f*b0};      // -2q (dot-product folding)
    f32x2 Qn1 = {-2.0f*a1, -2.0f*b1};
    f32x2 Qn2 = {-2.0f*a2, -2.0f*b2};
    f32x2 QE  = {a0*a0 + a1*a1 + a2*a2, b0*b0 + b1*b1 + b2*b2};

    float av_a=0.f, ac_a=0.f, ax_a=0.f, ay_a=0.f, az_a=0.f;
    float av_b=0.f, ac_b=0.f, ax_b=0.f, ay_b=0.f, az_b=0.f;

    __syncthreads();

    const int base = w * SLICE;
#pragma unroll 8
    for (int i = 0; i < SLICE; ++i) {
        const float4 p = pack[base + i];   // ONE broadcast ds_read_b128
        f32x2 P01 = {p.x, p.y};            // (y0, y1)
        f32x2 P2G = {p.z, p.w};            // (y2, g)

        // n2 = y.y + eps^2 (landmark-uniform)
        float n2 = fmaf(p.x, p.x, fmaf(p.y, p.y, fmaf(p.z, p.z, EPS2)));

        // T = QE - 2 q.y   (HW-validated twice via v_hat in R5/R6)
        f32x2 T;
        asm("v_pk_fma_f32 %0, %1, %2, %3 op_sel:[0,0,0] op_sel_hi:[0,1,1]\n\t"
            "v_pk_fma_f32 %0, %4, %5, %0 op_sel:[1,0,0] op_sel_hi:[1,1,1]\n\t"
            "v_pk_fma_f32 %0, %4, %6, %0 op_sel:[0,0,0] op_sel_hi:[0,1,1]"
            : "=&v"(T)
            : "v"(P2G), "v"(Qn2), "v"(QE), "v"(P01), "v"(Qn1), "v"(Qn0));

        // t = max(r2 + eps^2, eps^2) == maximum(r2,0)+eps^2 ; scalar from here
        float ta = fmaxf(T.x + n2, EPS2);
        float tb = fmaxf(T.y + n2, EPS2);
        float sa = __builtin_amdgcn_rsqf(ta);
        float sb = __builtin_amdgcn_rsqf(tb);

        float s3a = sa * sa * sa;
        float s3b = sb * sb * sb;
        float ca  = p.w * s3a;             // c = g * s^3
        float cb  = p.w * s3b;

        av_a = fmaf(p.w, sa, av_a);   av_b = fmaf(p.w, sb, av_b);   // Σ g·s
        ac_a += ca;                   ac_b += cb;                   // Σ c
        ax_a = fmaf(ca, p.x, ax_a);   ax_b = fmaf(cb, p.x, ax_b);   // Σ c·y0
        ay_a = fmaf(ca, p.y, ay_a);   ay_b = fmaf(cb, p.y, ay_b);   // Σ c·y1
        az_a = fmaf(ca, p.z, az_a);   az_b = fmaf(cb, p.z, az_b);   // Σ c·y2
    }

    // ---- per-(wave, query) partials ----
    part[w][lane][0] = av_a;  part[w][lane][1] = ac_a;
    part[w][lane][2] = ax_a;  part[w][lane][3] = ay_a;  part[w][lane][4] = az_a;
    part[w][lane+64][0] = av_b;  part[w][lane+64][1] = ac_b;
    part[w][lane+64][2] = ax_b;  part[w][lane+64][3] = ay_b;  part[w][lane+64][4] = az_b;

    __syncthreads();

    if (tid < 512) {
        const int q   = tid >> 2;
        const int cmp = tid & 3;
        const int qg  = qbase + q;
        if (cmp == 0) {
            float s = 0.f;
            #pragma unroll
            for (int ww = 0; ww < NW; ++ww) s += part[ww][q][0];
            out[qg] = s * (INV_4PI / (float)M_LAND);
        } else {
            float sc = 0.f, sy = 0.f;
            #pragma unroll
            for (int ww = 0; ww < NW; ++ww) {
                sc += part[ww][q][1];
                sy += part[ww][q][1 + cmp];    // Σ c·y_c
            }
            const float qc = xq[3*qg + (cmp-1)];
            // grad_c = -inv4pi/M * (q_c·Σc - Σ c·y_c)
            out[B + 3*qg + (cmp-1)] =
                (-INV_4PI / (float)M_LAND) * fmaf(qc, sc, -sy);
        }
    }
}

extern "C" void kernel_launch(void* const* d_in, const int* in_sizes, int n_in,
                              void* d_out, int out_size, void* d_ws, size_t ws_size,
                              hipStream_t stream)
{
    const float* xq = (const float*)d_in[0];   // (B,3)
    const float* xl = (const float*)d_in[1];   // (M,3)
    const float* gl = (const float*)d_in[2];   // (M,)
    float* out = (float*)d_out;

    const int B    = in_sizes[0] / 3;          // 32768
    const int grid = B / QPB;                  // 256 blocks (1 per CU)

    poisson_r7_kernel<<<grid, 1024, 0, stream>>>(xq, xl, gl, out, B);
}

// Round 9
// 28.089 us; speedup vs baseline: 1.1113x; 1.1113x over previous
//
#include <hip/hip_runtime.h>
#include <math.h>

// Poisson MC estimator. R9: R4's pk asm FROZEN VERBATIM (the only block-2
// that ever passed on silicon; R5/R6/R8 all corrupted the gradient with
// novel VOP3P variants). Performance model refit over R2/R4/R7: R4 is
// LDS-pipe-bound (4096 broadcast ds_read_b128/CU x ~16cy ~= 27us ~= measured
// 26.9). Lever: amortize each landmark read over 4 queries/lane (NQ=4).
// Grid = 128 query-blocks x 4 M-splits = 512 blocks (2/CU, 8 waves each):
// reads/CU halve to 2048 (~13.7us); VALU ~7us/SIMD. Partials land in d_ws
// (2.6MB; observed ws ~268MB) and a tiny combine kernel finishes — fixed-
// order sums, fully deterministic, every output written exactly once.

#define EPS2    1e-4f
#define INV_4PI 0.07957747154594767f

constexpr int M_LAND = 2048;

typedef float f32x2 __attribute__((ext_vector_type(2)));

// ---- R4's silicon-validated pk compute, verbatim (DO NOT EDIT) ----
// Consumes per-iteration locals P01,P2W,G01,G2G from enclosing scope.
#define PAIR_COMPUTE(Q0_, Q1_, Q2_, QE_, AV_, AC_, AX_, AY_, AZ_) do { \
    f32x2 T; \
    asm("v_pk_add_f32 %0, %1, %2 op_sel:[0,1] op_sel_hi:[1,1]\n\t" \
        "v_pk_fma_f32 %0, %2, %3, %0 op_sel:[0,0,0] op_sel_hi:[0,1,1]\n\t" \
        "v_pk_fma_f32 %0, %4, %5, %0 op_sel:[1,0,0] op_sel_hi:[1,1,1]\n\t" \
        "v_pk_fma_f32 %0, %4, %6, %0 op_sel:[0,0,0] op_sel_hi:[0,1,1]" \
        : "=&v"(T) \
        : "v"(QE_), "v"(P2W), "v"(Q2_), "v"(P01), "v"(Q1_), "v"(Q0_)); \
    float ta = fmaxf(T.x, EPS2); \
    float tb = fmaxf(T.y, EPS2); \
    f32x2 S = { __builtin_amdgcn_rsqf(ta), __builtin_amdgcn_rsqf(tb) }; \
    f32x2 S2, S3; \
    asm("v_pk_mul_f32 %0, %7, %7 op_sel:[0,0] op_sel_hi:[1,1]\n\t" \
        "v_pk_mul_f32 %1, %0, %7 op_sel:[0,0] op_sel_hi:[1,1]\n\t" \
        "v_pk_fma_f32 %2, %8, %7, %2 op_sel:[1,0,0] op_sel_hi:[1,1,1]\n\t" \
        "v_pk_fma_f32 %3, %8, %1, %3 op_sel:[1,0,0] op_sel_hi:[1,1,1]\n\t" \
        "v_pk_fma_f32 %4, %1, %9, %4 op_sel:[0,0,0] op_sel_hi:[1,0,1]\n\t" \
        "v_pk_fma_f32 %5, %1, %9, %5 op_sel:[0,1,0] op_sel_hi:[1,1,1]\n\t" \
        "v_pk_fma_f32 %6, %1, %8, %6 op_sel:[0,0,0] op_sel_hi:[1,0,1]" \
        : "=&v"(S2), "=&v"(S3), \
          "+v"(AV_), "+v"(AC_), "+v"(AX_), "+v"(AY_), "+v"(AZ_) \
        : "v"(S), "v"(G2G), "v"(G01)); \
} while (0)

// ================= main partials kernel =================
// grid 512 = 128 query-blocks x 4 M-splits; block = 512 thr = 8 waves.
// Each lane owns 4 queries (lane, +64, +128, +192) as two packed pairs.
// Wave w handles landmark slice [w*64, w*64+64) of this block's M-split.
__global__ __launch_bounds__(512, 4)
void poisson_part_kernel(const float* __restrict__ xq,
                         const float* __restrict__ xl,
                         const float* __restrict__ gl,
                         float* __restrict__ ws)
{
    __shared__ float4 pack[512];           //  8 KB: (-2y0,-2y1,-2y2, n2+eps^2)
    __shared__ float4 gpack[512];          //  8 KB: (-2gy0,-2gy1,-2gy2, g)
    __shared__ float  part[8][256][5];     // 40 KB

    const int tid  = threadIdx.x;
    const int qblk = blockIdx.x >> 2;      // 0..127
    const int ms   = blockIdx.x & 3;       // M-split 0..3

    // ---- stage this block's 512 landmarks (1 per thread) ----
    {
        int jg = ms * 512 + tid;
        float l0 = xl[3*jg], l1 = xl[3*jg+1], l2 = xl[3*jg+2], g = gl[jg];
        float n2 = l0*l0 + l1*l1 + l2*l2 + EPS2;
        pack[tid]  = make_float4(-2.0f*l0, -2.0f*l1, -2.0f*l2, n2);
        gpack[tid] = make_float4(-2.0f*g*l0, -2.0f*g*l1, -2.0f*g*l2, g);
    }

    const int lane  = tid & 63;
    const int w     = tid >> 6;            // 0..7
    const int qbase = qblk * 256;

    const int qa = qbase + lane,       qbq = qbase + 64  + lane;
    const int qc = qbase + 128 + lane, qd  = qbase + 192 + lane;

    const float a0 = xq[3*qa], a1 = xq[3*qa+1], a2 = xq[3*qa+2];
    const float b0 = xq[3*qbq], b1 = xq[3*qbq+1], b2 = xq[3*qbq+2];
    const float c0 = xq[3*qc], c1 = xq[3*qc+1], c2 = xq[3*qc+2];
    const float d0 = xq[3*qd], d1 = xq[3*qd+1], d2 = xq[3*qd+2];

    // pair A = (qa, qbq), pair B = (qc, qd); lo/hi of each f32x2
    f32x2 Q0a = {a0, b0}, Q1a = {a1, b1}, Q2a = {a2, b2};
    f32x2 QEa = {a0*a0 + a1*a1 + a2*a2, b0*b0 + b1*b1 + b2*b2};
    f32x2 Q0b = {c0, d0}, Q1b = {c1, d1}, Q2b = {c2, d2};
    f32x2 QEb = {c0*c0 + c1*c1 + c2*c2, d0*d0 + d1*d1 + d2*d2};

    f32x2 AVa = {0,0}, ACa = {0,0}, AXa = {0,0}, AYa = {0,0}, AZa = {0,0};
    f32x2 AVb = {0,0}, ACb = {0,0}, AXb = {0,0}, AYb = {0,0}, AZb = {0,0};

    __syncthreads();

    const int base = w * 64;
#pragma unroll 4
    for (int i = 0; i < 64; ++i) {
        const float4 p  = pack[base + i];   // broadcast ds_read_b128
        const float4 gp = gpack[base + i];  // broadcast ds_read_b128
        f32x2 P01 = {p.x,  p.y};
        f32x2 P2W = {p.z,  p.w};
        f32x2 G01 = {gp.x, gp.y};
        f32x2 G2G = {gp.z, gp.w};
        PAIR_COMPUTE(Q0a, Q1a, Q2a, QEa, AVa, ACa, AXa, AYa, AZa);
        PAIR_COMPUTE(Q0b, Q1b, Q2b, QEb, AVb, ACb, AXb, AYb, AZb);
    }

    // ---- per-(wave, query) partials ----
    part[w][lane][0] = AVa.x;  part[w][lane][1] = ACa.x;
    part[w][lane][2] = AXa.x;  part[w][lane][3] = AYa.x;  part[w][lane][4] = AZa.x;
    part[w][lane+64][0] = AVa.y;  part[w][lane+64][1] = ACa.y;
    part[w][lane+64][2] = AXa.y;  part[w][lane+64][3] = AYa.y;  part[w][lane+64][4] = AZa.y;
    part[w][lane+128][0] = AVb.x;  part[w][lane+128][1] = ACb.x;
    part[w][lane+128][2] = AXb.x;  part[w][lane+128][3] = AYb.x;  part[w][lane+128][4] = AZb.x;
    part[w][lane+192][0] = AVb.y;  part[w][lane+192][1] = ACb.y;
    part[w][lane+192][2] = AXb.y;  part[w][lane+192][3] = AYb.y;  part[w][lane+192][4] = AZb.y;

    __syncthreads();

    // ---- reduce 8 waves, write block partials to ws[bid][comp][qloc] ----
    for (int s = tid; s < 1280; s += 512) {
        const int comp = s >> 8;           // 0..4
        const int qloc = s & 255;
        float acc = 0.f;
        #pragma unroll
        for (int ww = 0; ww < 8; ++ww) acc += part[ww][qloc][comp];
        ws[(size_t)blockIdx.x * 1280 + s] = acc;
    }
}

// ================= combine kernel =================
// 131072 threads: one per (query, component). Fixed-order 4-way sums.
__global__ __launch_bounds__(512)
void poisson_combine_kernel(const float* __restrict__ ws,
                            const float* __restrict__ xq,
                            float* __restrict__ out, int B)
{
    const int gid  = blockIdx.x * 512 + threadIdx.x;   // 0..131071
    const int q    = gid >> 2;
    const int cmp  = gid & 3;
    const int qblk = q >> 8;
    const int qloc = q & 255;
    const float* wbase = ws + (size_t)qblk * 4 * 1280;

    if (cmp == 0) {
        float s = 0.f;
        #pragma unroll
        for (int m = 0; m < 4; ++m) s += wbase[m*1280 + qloc];
        out[q] = s * (INV_4PI / (float)M_LAND);
    } else {
        float sc = 0.f, sy = 0.f;
        #pragma unroll
        for (int m = 0; m < 4; ++m) {
            sc += wbase[m*1280 + 256 + qloc];
            sy += wbase[m*1280 + (1+cmp)*256 + qloc];  // Σ c*(-2 y_c)
        }
        const float qc = xq[3*q + (cmp-1)];
        // grad_c = -inv4pi/M * (q_c*Σc + sy/2)
        out[B + 3*q + (cmp-1)] =
            (-INV_4PI / (float)M_LAND) * fmaf(qc, sc, 0.5f * sy);
    }
}

// ================= fallback: R4 kernel verbatim (proven, 26.9us) =================
constexpr int NW_F  = 16;
constexpr int SL_F  = M_LAND / NW_F;
constexpr int QPB_F = 128;

__global__ __launch_bounds__(1024, 4)
void poisson_pk_kernel(const float* __restrict__ xq,
                       const float* __restrict__ xl,
                       const float* __restrict__ gl,
                       float* __restrict__ out, int B)
{
    __shared__ float4 pack[M_LAND];
    __shared__ float4 gpack[M_LAND];
    __shared__ float  part[NW_F][QPB_F][5];

    const int tid = threadIdx.x;
    for (int j = tid; j < M_LAND; j += 1024) {
        float l0 = xl[3*j], l1 = xl[3*j+1], l2 = xl[3*j+2], g = gl[j];
        float n2 = l0*l0 + l1*l1 + l2*l2 + EPS2;
        pack[j]  = make_float4(-2.0f*l0, -2.0f*l1, -2.0f*l2, n2);
        gpack[j] = make_float4(-2.0f*g*l0, -2.0f*g*l1, -2.0f*g*l2, g);
    }
    const int lane = tid & 63, w = tid >> 6;
    const int qbase = blockIdx.x * QPB_F;
    const int qa = qbase + lane, qb = qbase + 64 + lane;
    const float a0 = xq[3*qa], a1 = xq[3*qa+1], a2 = xq[3*qa+2];
    const float b0 = xq[3*qb], b1 = xq[3*qb+1], b2 = xq[3*qb+2];
    f32x2 Q0 = {a0, b0}, Q1 = {a1, b1}, Q2 = {a2, b2};
    f32x2 QE = {a0*a0 + a1*a1 + a2*a2, b0*b0 + b1*b1 + b2*b2};
    f32x2 AV = {0,0}, AC = {0,0}, AX = {0,0}, AY = {0,0}, AZ = {0,0};
    __syncthreads();

    const int base = w * SL_F;
#pragma unroll 8
    for (int i = 0; i < SL_F; ++i) {
        const float4 p  = pack[base + i];
        const float4 gp = gpack[base + i];
        f32x2 P01 = {p.x,  p.y};
        f32x2 P2W = {p.z,  p.w};
        f32x2 G01 = {gp.x, gp.y};
        f32x2 G2G = {gp.z, gp.w};
        PAIR_COMPUTE(Q0, Q1, Q2, QE, AV, AC, AX, AY, AZ);
    }
    part[w][lane][0] = AV.x;  part[w][lane][1] = AC.x;
    part[w][lane][2] = AX.x;  part[w][lane][3] = AY.x;  part[w][lane][4] = AZ.x;
    part[w][lane+64][0] = AV.y;  part[w][lane+64][1] = AC.y;
    part[w][lane+64][2] = AX.y;  part[w][lane+64][3] = AY.y;  part[w][lane+64][4] = AZ.y;
    __syncthreads();
    if (tid < 512) {
        const int q = tid >> 2, cmp = tid & 3, qg = qbase + q;
        if (cmp == 0) {
            float s = 0.f;
            #pragma unroll
            for (int ww = 0; ww < NW_F; ++ww) s += part[ww][q][0];
            out[qg] = s * (INV_4PI / (float)M_LAND);
        } else {
            float sc = 0.f, sy = 0.f;
            #pragma unroll
            for (int ww = 0; ww < NW_F; ++ww) {
                sc += part[ww][q][1];
                sy += part[ww][q][1 + cmp];
            }
            const float qc = xq[3*qg + (cmp-1)];
            out[B + 3*qg + (cmp-1)] =
                (-INV_4PI / (float)M_LAND) * fmaf(qc, sc, 0.5f * sy);
        }
    }
}

extern "C" void kernel_launch(void* const* d_in, const int* in_sizes, int n_in,
                              void* d_out, int out_size, void* d_ws, size_t ws_size,
                              hipStream_t stream)
{
    const float* xq = (const float*)d_in[0];   // (B,3)
    const float* xl = (const float*)d_in[1];   // (M,3)
    const float* gl = (const float*)d_in[2];   // (M,)
    float* out = (float*)d_out;

    const int B = in_sizes[0] / 3;             // 32768

    const size_t need = (size_t)512 * 1280 * sizeof(float);   // 2.62 MB
    if (ws_size >= need && B == 32768) {
        float* ws = (float*)d_ws;
        poisson_part_kernel<<<512, 512, 0, stream>>>(xq, xl, gl, ws);
        poisson_combine_kernel<<<256, 512, 0, stream>>>(ws, xq, out, B);
    } else {
        poisson_pk_kernel<<<B / QPB_F, 1024, 0, stream>>>(xq, xl, gl, out, B);
    }
}